// Round 1
// baseline (704.138 us; speedup 1.0000x reference)
//
#include <hip/hip_runtime.h>

#define BB 32
#define CC 128
#define HH 96
#define WW 96
#define BN_EPS 1e-5f

// One block: batch bb, spatial tile 8 (h) x 16 (w) = 128 pixels, all 128 channels.
// Stage 1: depthwise 3x3 -> LDS xn[c][p] (64 KB)
// Stage 2: pointwise 128x128 GEMM (fp32 VALU) + BN + ReLU -> out
__global__ __launch_bounds__(256, 2)
void fused_dwconv_pw_bn_relu(const float* __restrict__ x,
                             const float* __restrict__ kk,
                             const float* __restrict__ pw,
                             const float* __restrict__ bng,
                             const float* __restrict__ bnb,
                             const float* __restrict__ bnm,
                             const float* __restrict__ bnv,
                             float* __restrict__ out)
{
    __shared__ float xn[128 * 128];   // xn[c][p], p = py*16 + px

    const int tid = threadIdx.x;
    const int w0 = blockIdx.x * 16;
    const int h0 = blockIdx.y * 8;
    const int bb = blockIdx.z;

    // ---------------- stage 1: depthwise 3x3 ----------------
    {
        const int p  = tid & 127;                                   // pixel in tile
        const int c0 = __builtin_amdgcn_readfirstlane(tid >> 7);    // 0 or 1, wave-uniform
        const int py = p >> 4;
        const int px = p & 15;
        const int gh = h0 + py;
        const int gw = w0 + px;
        const bool t_ok = gh >= 1;
        const bool b_ok = (gh + 1) < HH;
        const bool l_ok = gw >= 1;
        const bool r_ok = (gw + 1) < WW;

        #pragma unroll 2
        for (int ic = 0; ic < 64; ++ic) {
            const int c = ic * 2 + c0;                               // wave-uniform channel
            const float* xp = x  + ((size_t)(bb * CC + c) * HH) * WW;
            const float* kp = kk + (size_t)(bb * CC + c) * 9;
            const float k00 = kp[0], k01 = kp[1], k02 = kp[2];
            const float k10 = kp[3], k11 = kp[4], k12 = kp[5];
            const float k20 = kp[6], k21 = kp[7], k22 = kp[8];
            const float* r0 = xp + (size_t)(gh - 1) * WW + gw;
            const float* r1 = xp + (size_t)gh * WW + gw;
            const float* r2 = xp + (size_t)(gh + 1) * WW + gw;
            float s = 0.f, v;
            v = (t_ok && l_ok) ? r0[-1] : 0.f; s = fmaf(v, k00, s);
            v =  t_ok          ? r0[0]  : 0.f; s = fmaf(v, k01, s);
            v = (t_ok && r_ok) ? r0[1]  : 0.f; s = fmaf(v, k02, s);
            v =  l_ok          ? r1[-1] : 0.f; s = fmaf(v, k10, s);
            v =                  r1[0];        s = fmaf(v, k11, s);
            v =  r_ok          ? r1[1]  : 0.f; s = fmaf(v, k12, s);
            v = (b_ok && l_ok) ? r2[-1] : 0.f; s = fmaf(v, k20, s);
            v =  b_ok          ? r2[0]  : 0.f; s = fmaf(v, k21, s);
            v = (b_ok && r_ok) ? r2[1]  : 0.f; s = fmaf(v, k22, s);
            xn[c * 128 + p] = s;
        }
    }

    __syncthreads();

    // -------- stage 2: pointwise GEMM (o = 32 per wave, 128 px) + BN + ReLU --------
    {
        const int lane  = tid & 63;
        const int wv    = __builtin_amdgcn_readfirstlane(tid >> 6); // 0..3, wave-uniform
        const int obase = wv * 32;

        float acc[32][2];
        #pragma unroll
        for (int i = 0; i < 32; ++i) { acc[i][0] = 0.f; acc[i][1] = 0.f; }

        #pragma unroll 1
        for (int cb = 0; cb < 16; ++cb) {
            float xv0[8], xv1[8];
            #pragma unroll
            for (int j = 0; j < 8; ++j) {
                xv0[j] = xn[(cb * 8 + j) * 128 + lane];
                xv1[j] = xn[(cb * 8 + j) * 128 + 64 + lane];
            }
            #pragma unroll
            for (int ot = 0; ot < 4; ++ot) {
                #pragma unroll
                for (int oo = 0; oo < 8; ++oo) {
                    // wave-uniform address -> scalar loads (pw row chunk of 8)
                    const float* pr = pw + (size_t)(obase + ot * 8 + oo) * 128 + cb * 8;
                    #pragma unroll
                    for (int j = 0; j < 8; ++j) {
                        const float wgt = pr[j];
                        acc[ot * 8 + oo][0] = fmaf(wgt, xv0[j], acc[ot * 8 + oo][0]);
                        acc[ot * 8 + oo][1] = fmaf(wgt, xv1[j], acc[ot * 8 + oo][1]);
                    }
                }
            }
        }

        // epilogue: BN (inference) + ReLU + store
        #pragma unroll 1
        for (int idx = 0; idx < 32; ++idx) {
            const int o = obase + idx;
            const float inv  = bng[o] * rsqrtf(bnv[o] + BN_EPS);
            const float bias = bnb[o] - bnm[o] * inv;
            #pragma unroll
            for (int s = 0; s < 2; ++s) {
                const int p  = lane + 64 * s;
                const int py = p >> 4;
                const int px = p & 15;
                float v = fmaf(acc[idx][s], inv, bias);
                v = fmaxf(v, 0.f);
                out[(((size_t)(bb * CC + o)) * HH + (h0 + py)) * WW + (w0 + px)] = v;
            }
        }
    }
}

extern "C" void kernel_launch(void* const* d_in, const int* in_sizes, int n_in,
                              void* d_out, int out_size, void* d_ws, size_t ws_size,
                              hipStream_t stream) {
    const float* x   = (const float*)d_in[0];
    const float* kk  = (const float*)d_in[1];
    const float* pwt = (const float*)d_in[2];
    const float* g   = (const float*)d_in[3];
    const float* b   = (const float*)d_in[4];
    const float* m   = (const float*)d_in[5];
    const float* v   = (const float*)d_in[6];
    float* out = (float*)d_out;

    dim3 grid(WW / 16, HH / 8, BB);   // 6 x 12 x 32 = 2304 blocks
    fused_dwconv_pw_bn_relu<<<grid, dim3(256), 0, stream>>>(x, kk, pwt, g, b, m, v, out);
}

// Round 2
// 510.263 us; speedup vs baseline: 1.3800x; 1.3800x over previous
//
#include <hip/hip_runtime.h>

#define BB 32
#define CC 128
#define HH 96
#define WW 96
#define BN_EPS 1e-5f

// One block: batch bb, spatial tile 8 (h) x 16 (w) = 128 pixels, all 128 channels.
// Stage 1: depthwise 3x3 -> LDS xn[c][p] (64 KB)
// Stage 2: pointwise 128x128 GEMM (fp32 VALU) + BN + ReLU -> out
// R2 fix: epilogue fully unrolled -> acc[][] statically indexed -> stays in VGPRs
//         (R1 had "#pragma unroll 1" there; runtime acc[idx] demoted the whole
//          accumulator to scratch: WRITE_SIZE 2.2 GB, 14x write amplification)
__global__ __launch_bounds__(256, 2)
void fused_dwconv_pw_bn_relu(const float* __restrict__ x,
                             const float* __restrict__ kk,
                             const float* __restrict__ pw,
                             const float* __restrict__ bng,
                             const float* __restrict__ bnb,
                             const float* __restrict__ bnm,
                             const float* __restrict__ bnv,
                             float* __restrict__ out)
{
    __shared__ float xn[128 * 128];   // xn[c][p], p = py*16 + px

    const int tid = threadIdx.x;
    const int w0 = blockIdx.x * 16;
    const int h0 = blockIdx.y * 8;
    const int bb = blockIdx.z;

    // ---------------- stage 1: depthwise 3x3 ----------------
    {
        const int p  = tid & 127;                                   // pixel in tile
        const int c0 = __builtin_amdgcn_readfirstlane(tid >> 7);    // 0 or 1, wave-uniform
        const int py = p >> 4;
        const int px = p & 15;
        const int gh = h0 + py;
        const int gw = w0 + px;
        const bool t_ok = gh >= 1;
        const bool b_ok = (gh + 1) < HH;
        const bool l_ok = gw >= 1;
        const bool r_ok = (gw + 1) < WW;

        #pragma unroll 2
        for (int ic = 0; ic < 64; ++ic) {
            const int c = ic * 2 + c0;                               // wave-uniform channel
            const float* xp = x  + ((size_t)(bb * CC + c) * HH) * WW;
            const float* kp = kk + (size_t)(bb * CC + c) * 9;
            const float k00 = kp[0], k01 = kp[1], k02 = kp[2];
            const float k10 = kp[3], k11 = kp[4], k12 = kp[5];
            const float k20 = kp[6], k21 = kp[7], k22 = kp[8];
            const float* r0 = xp + (size_t)(gh - 1) * WW + gw;
            const float* r1 = xp + (size_t)gh * WW + gw;
            const float* r2 = xp + (size_t)(gh + 1) * WW + gw;
            float s = 0.f, v;
            v = (t_ok && l_ok) ? r0[-1] : 0.f; s = fmaf(v, k00, s);
            v =  t_ok          ? r0[0]  : 0.f; s = fmaf(v, k01, s);
            v = (t_ok && r_ok) ? r0[1]  : 0.f; s = fmaf(v, k02, s);
            v =  l_ok          ? r1[-1] : 0.f; s = fmaf(v, k10, s);
            v =                  r1[0];        s = fmaf(v, k11, s);
            v =  r_ok          ? r1[1]  : 0.f; s = fmaf(v, k12, s);
            v = (b_ok && l_ok) ? r2[-1] : 0.f; s = fmaf(v, k20, s);
            v =  b_ok          ? r2[0]  : 0.f; s = fmaf(v, k21, s);
            v = (b_ok && r_ok) ? r2[1]  : 0.f; s = fmaf(v, k22, s);
            xn[c * 128 + p] = s;
        }
    }

    __syncthreads();

    // -------- stage 2: pointwise GEMM (o = 32 per wave, 128 px) + BN + ReLU --------
    {
        const int lane  = tid & 63;
        const int wv    = __builtin_amdgcn_readfirstlane(tid >> 6); // 0..3, wave-uniform
        const int obase = wv * 32;

        float acc[32][2];
        #pragma unroll
        for (int i = 0; i < 32; ++i) { acc[i][0] = 0.f; acc[i][1] = 0.f; }

        #pragma unroll 1
        for (int cb = 0; cb < 16; ++cb) {
            float xv0[8], xv1[8];
            #pragma unroll
            for (int j = 0; j < 8; ++j) {
                xv0[j] = xn[(cb * 8 + j) * 128 + lane];
                xv1[j] = xn[(cb * 8 + j) * 128 + 64 + lane];
            }
            #pragma unroll
            for (int ot = 0; ot < 4; ++ot) {
                #pragma unroll
                for (int oo = 0; oo < 8; ++oo) {
                    // wave-uniform address -> scalar loads (pw row chunk of 8)
                    const float* pr = pw + (size_t)(obase + ot * 8 + oo) * 128 + cb * 8;
                    #pragma unroll
                    for (int j = 0; j < 8; ++j) {
                        const float wgt = pr[j];
                        acc[ot * 8 + oo][0] = fmaf(wgt, xv0[j], acc[ot * 8 + oo][0]);
                        acc[ot * 8 + oo][1] = fmaf(wgt, xv1[j], acc[ot * 8 + oo][1]);
                    }
                }
            }
        }

        // epilogue: BN (inference) + ReLU + store  (FULLY unrolled: static acc idx)
        #pragma unroll
        for (int idx = 0; idx < 32; ++idx) {
            const int o = obase + idx;
            const float inv  = bng[o] * rsqrtf(bnv[o] + BN_EPS);
            const float bias = bnb[o] - bnm[o] * inv;
            #pragma unroll
            for (int s = 0; s < 2; ++s) {
                const int p  = lane + 64 * s;
                const int py = p >> 4;
                const int px = p & 15;
                float v = fmaf(acc[idx][s], inv, bias);
                v = fmaxf(v, 0.f);
                out[(((size_t)(bb * CC + o)) * HH + (h0 + py)) * WW + (w0 + px)] = v;
            }
        }
    }
}

extern "C" void kernel_launch(void* const* d_in, const int* in_sizes, int n_in,
                              void* d_out, int out_size, void* d_ws, size_t ws_size,
                              hipStream_t stream) {
    const float* x   = (const float*)d_in[0];
    const float* kk  = (const float*)d_in[1];
    const float* pwt = (const float*)d_in[2];
    const float* g   = (const float*)d_in[3];
    const float* b   = (const float*)d_in[4];
    const float* m   = (const float*)d_in[5];
    const float* v   = (const float*)d_in[6];
    float* out = (float*)d_out;

    dim3 grid(WW / 16, HH / 8, BB);   // 6 x 12 x 32 = 2304 blocks
    fused_dwconv_pw_bn_relu<<<grid, dim3(256), 0, stream>>>(x, kk, pwt, g, b, m, v, out);
}

// Round 3
// 169.646 us; speedup vs baseline: 4.1506x; 3.0078x over previous
//
#include <hip/hip_runtime.h>
#include <hip/hip_bf16.h>

#define BB 32
#define CC 128
#define HH 96
#define WW 96
#define BN_EPS 1e-5f

typedef __attribute__((ext_vector_type(8))) short bf16x8_t;
typedef __attribute__((ext_vector_type(4))) float f32x4_t;

// ---------------------------------------------------------------------------
// Prep: W fp32 -> bf16, k-permuted for mfma_f32_16x16x32_bf16 split-k frags
//   storage cidx = kc*32 + g*8 + j  <->  actual c = kc*32 + g*4 + (j&3) + 16*(j>>2)
// Also folds BN to inv/bias.
// ---------------------------------------------------------------------------
__global__ __launch_bounds__(256)
void prep_kernel(const float* __restrict__ pw,
                 const float* __restrict__ g, const float* __restrict__ b,
                 const float* __restrict__ m, const float* __restrict__ v,
                 unsigned short* __restrict__ wper,
                 float* __restrict__ inv, float* __restrict__ bias)
{
    int t = blockIdx.x * 256 + threadIdx.x;
    if (t < CC * CC) {
        int o = t >> 7, cidx = t & 127;
        int kc = cidx >> 5, r = cidx & 31, gg = r >> 3, j = r & 7;
        int c = kc * 32 + gg * 4 + (j & 3) + 16 * (j >> 2);
        __hip_bfloat16 h = __float2bfloat16(pw[o * CC + c]);
        wper[o * CC + cidx] = *reinterpret_cast<unsigned short*>(&h);
    }
    if (t < CC) {
        float iv = g[t] * rsqrtf(v[t] + BN_EPS);
        inv[t] = iv;
        bias[t] = b[t] - m[t] * iv;
    }
}

// ---------------------------------------------------------------------------
// Main: one block = batch bb x (16w x 8h) tile, all 128 channels.
// Stage 1: depthwise 3x3, sliding window in h (2-row register reuse),
//          thread = (px, 8-channel permuted group), b128 swizzled LDS writes.
// Stage 2: 128x128x128 bf16 MFMA GEMM + BN + ReLU.
// LDS xn[p][c] bf16, byte-swizzle: col ^= ((p&7)<<4)  (G4: stride-256B rows)
// ---------------------------------------------------------------------------
__global__ __launch_bounds__(256)
void fused_main(const float* __restrict__ x, const float* __restrict__ kk,
                const unsigned short* __restrict__ wper,
                const float* __restrict__ invp, const float* __restrict__ biasp,
                float* __restrict__ out)
{
    __shared__ unsigned char xnb[128 * 256];

    const int tid = threadIdx.x;
    const int w0 = blockIdx.x * 16;
    const int h0 = blockIdx.y * 8;
    const int bb = blockIdx.z;

    // ---------------- stage 1: depthwise ----------------
    {
        const int px    = tid & 15;
        const int cg    = tid >> 4;        // 0..15: group of 8 storage channels
        const int chunk = cg >> 2;         // 32-ch k-chunk
        const int gg    = cg & 3;
        const int gw    = w0 + px;
        const bool l_ok = gw >= 1;
        const bool r_ok = gw + 1 < WW;
        const int gwm = l_ok ? gw - 1 : 0;
        const int gwp = r_ok ? gw + 1 : WW - 1;

        int   xoff[8];
        float kw[8][9];
        #pragma unroll
        for (int j = 0; j < 8; ++j) {
            const int c = chunk * 32 + gg * 4 + (j & 3) + 16 * (j >> 2);
            xoff[j] = (bb * CC + c) * (HH * WW);
            const float* kp = kk + (size_t)(bb * CC + c) * 9;
            #pragma unroll
            for (int t = 0; t < 9; ++t) kw[j][t] = kp[t];
        }

        float rA[8][3], rB[8][3];

        auto load_row = [&](int j, int row, float* dst) {
            const int rr = row < 0 ? 0 : (row >= HH ? HH - 1 : row);
            const float* rp = x + xoff[j] + rr * WW;
            float v0 = rp[gwm], v1 = rp[gw], v2 = rp[gwp];
            if (row < 0 || row >= HH) { v0 = 0.f; v1 = 0.f; v2 = 0.f; }  // block-uniform
            dst[0] = l_ok ? v0 : 0.f;
            dst[1] = v1;
            dst[2] = r_ok ? v2 : 0.f;
        };

        #pragma unroll
        for (int j = 0; j < 8; ++j) {
            load_row(j, h0 - 1, rA[j]);
            load_row(j, h0, rB[j]);
        }

        #pragma unroll
        for (int py = 0; py < 8; ++py) {
            bf16x8_t pk;
            #pragma unroll
            for (int j = 0; j < 8; ++j) {
                float rC[3];
                load_row(j, h0 + py + 1, rC);
                float s = 0.f;
                s = fmaf(rA[j][0], kw[j][0], s);
                s = fmaf(rA[j][1], kw[j][1], s);
                s = fmaf(rA[j][2], kw[j][2], s);
                s = fmaf(rB[j][0], kw[j][3], s);
                s = fmaf(rB[j][1], kw[j][4], s);
                s = fmaf(rB[j][2], kw[j][5], s);
                s = fmaf(rC[0],    kw[j][6], s);
                s = fmaf(rC[1],    kw[j][7], s);
                s = fmaf(rC[2],    kw[j][8], s);
                __hip_bfloat16 h = __float2bfloat16(s);
                pk[j] = *reinterpret_cast<short*>(&h);
                rA[j][0] = rB[j][0]; rA[j][1] = rB[j][1]; rA[j][2] = rB[j][2];
                rB[j][0] = rC[0];    rB[j][1] = rC[1];    rB[j][2] = rC[2];
            }
            const int p = py * 16 + px;                  // p&7 == px&7
            const unsigned col = (unsigned)(cg * 16) ^ (unsigned)((px & 7) << 4);
            *reinterpret_cast<bf16x8_t*>(&xnb[(unsigned)p * 256 + col]) = pk;
        }
    }

    __syncthreads();

    // ---------------- stage 2: MFMA pointwise + BN + ReLU ----------------
    {
        const int lane   = tid & 63;
        const int wv     = tid >> 6;       // 0..3
        const int lo     = lane & 15;
        const int hi     = lane >> 4;
        const int o_base = wv * 32;

        // A fragments (W): 2 o-tiles x 4 k-chunks, one 16B load each
        bf16x8_t afrag[2][4];
        #pragma unroll
        for (int t2 = 0; t2 < 2; ++t2)
            #pragma unroll
            for (int kc = 0; kc < 4; ++kc)
                afrag[t2][kc] = *reinterpret_cast<const bf16x8_t*>(
                    wper + (size_t)(o_base + t2 * 16 + lo) * CC + kc * 32 + hi * 8);

        f32x4_t acc[8][2];
        #pragma unroll
        for (int pt = 0; pt < 8; ++pt) {
            acc[pt][0] = (f32x4_t){0.f, 0.f, 0.f, 0.f};
            acc[pt][1] = (f32x4_t){0.f, 0.f, 0.f, 0.f};
        }

        #pragma unroll
        for (int pt = 0; pt < 8; ++pt) {
            const unsigned rowbase = (unsigned)(pt * 16 + lo) * 256;
            const unsigned sw = (unsigned)((lo & 7) << 4);
            #pragma unroll
            for (int kc = 0; kc < 4; ++kc) {
                bf16x8_t bfrag = *reinterpret_cast<const bf16x8_t*>(
                    &xnb[rowbase + (((unsigned)(kc * 64 + hi * 16)) ^ sw)]);
                acc[pt][0] = __builtin_amdgcn_mfma_f32_16x16x32_bf16(
                    afrag[0][kc], bfrag, acc[pt][0], 0, 0, 0);
                acc[pt][1] = __builtin_amdgcn_mfma_f32_16x16x32_bf16(
                    afrag[1][kc], bfrag, acc[pt][1], 0, 0, 0);
            }
        }

        float iv[2][4], bs[2][4];
        #pragma unroll
        for (int t2 = 0; t2 < 2; ++t2)
            #pragma unroll
            for (int r = 0; r < 4; ++r) {
                const int o = o_base + t2 * 16 + hi * 4 + r;
                iv[t2][r] = invp[o];
                bs[t2][r] = biasp[o];
            }

        #pragma unroll
        for (int pt = 0; pt < 8; ++pt) {
            const int hrow = h0 + pt;          // p-tile pt == one h row
            #pragma unroll
            for (int t2 = 0; t2 < 2; ++t2) {
                #pragma unroll
                for (int r = 0; r < 4; ++r) {
                    const int o = o_base + t2 * 16 + hi * 4 + r;
                    float val = fmaf(acc[pt][t2][r], iv[t2][r], bs[t2][r]);
                    val = fmaxf(val, 0.f);
                    out[((size_t)(bb * CC + o) * HH + hrow) * WW + w0 + lo] = val;
                }
            }
        }
    }
}

extern "C" void kernel_launch(void* const* d_in, const int* in_sizes, int n_in,
                              void* d_out, int out_size, void* d_ws, size_t ws_size,
                              hipStream_t stream) {
    const float* x   = (const float*)d_in[0];
    const float* kk  = (const float*)d_in[1];
    const float* pwt = (const float*)d_in[2];
    const float* g   = (const float*)d_in[3];
    const float* b   = (const float*)d_in[4];
    const float* m   = (const float*)d_in[5];
    const float* v   = (const float*)d_in[6];
    float* out = (float*)d_out;

    unsigned short* wper = (unsigned short*)d_ws;                 // 32 KB
    float* inv  = (float*)((char*)d_ws + 32768);                  // 512 B
    float* bias = (float*)((char*)d_ws + 32768 + 512);            // 512 B

    prep_kernel<<<64, 256, 0, stream>>>(pwt, g, b, m, v, wper, inv, bias);
    fused_main<<<dim3(WW / 16, HH / 8, BB), 256, 0, stream>>>(
        x, kk, wper, inv, bias, out);
}

// Round 4
// 132.658 us; speedup vs baseline: 5.3079x; 1.2788x over previous
//
#include <hip/hip_runtime.h>
#include <hip/hip_bf16.h>

#define BB 32
#define CC 128
#define HH 96
#define WW 96
#define BN_EPS 1e-5f

typedef __attribute__((ext_vector_type(8))) short bf16x8_t;
typedef __attribute__((ext_vector_type(4))) float f32x4_t;
typedef __attribute__((ext_vector_type(4), aligned(4))) float f32x4u_t;

// ---------------------------------------------------------------------------
// Prep: W fp32 -> bf16, k-permuted for mfma_f32_16x16x32_bf16 split-k frags
//   storage cidx = kc*32 + g*8 + j  <->  actual c = kc*32 + g*4 + (j&3) + 16*(j>>2)
// Also folds BN to inv/bias.   (unchanged from R3 — verified)
// ---------------------------------------------------------------------------
__global__ __launch_bounds__(256)
void prep_kernel(const float* __restrict__ pw,
                 const float* __restrict__ g, const float* __restrict__ b,
                 const float* __restrict__ m, const float* __restrict__ v,
                 unsigned short* __restrict__ wper,
                 float* __restrict__ inv, float* __restrict__ bias)
{
    int t = blockIdx.x * 256 + threadIdx.x;
    if (t < CC * CC) {
        int o = t >> 7, cidx = t & 127;
        int kc = cidx >> 5, r = cidx & 31, gg = r >> 3, j = r & 7;
        int c = kc * 32 + gg * 4 + (j & 3) + 16 * (j >> 2);
        __hip_bfloat16 h = __float2bfloat16(pw[o * CC + c]);
        wper[o * CC + cidx] = *reinterpret_cast<unsigned short*>(&h);
    }
    if (t < CC) {
        float iv = g[t] * rsqrtf(v[t] + BN_EPS);
        inv[t] = iv;
        bias[t] = b[t] - m[t] * iv;
    }
}

// ---------------------------------------------------------------------------
// Main: one block = batch bb x (16w x 8h) tile, all 128 channels.
// Stage 1 (R4 rewrite): thread = (w-quad, storage-channel-pair). Even storage
//   pairs map to CONSECUTIVE actual channels, so weights are 18 contiguous
//   floats (5 vector loads) and x reads are one aligned dwordx4 + 2 edge
//   scalars per (channel,row). Sliding 3-row register window over 8 output
//   rows. 65 VMEM/thread (was ~312 scalar in R3).
// Stage 2: bf16 MFMA 128x128x128 + BN + ReLU (unchanged from R3 — verified).
// LDS xn[p][c_storage] bf16, byte-swizzle boff ^= (p&7)<<4 on both sides.
// ---------------------------------------------------------------------------
__global__ __launch_bounds__(256, 4)
void fused_main(const float* __restrict__ x, const float* __restrict__ kk,
                const unsigned short* __restrict__ wper,
                const float* __restrict__ invp, const float* __restrict__ biasp,
                float* __restrict__ out)
{
    __shared__ __align__(16) unsigned char xnb[128 * 256];

    const int tid = threadIdx.x;
    const int w0 = blockIdx.x * 16;
    const int h0 = blockIdx.y * 8;
    const int bb = blockIdx.z;

    // ---------------- stage 1: depthwise ----------------
    {
        const int wq = tid & 3;            // 4-wide w quad
        const int cp = tid >> 2;           // 0..63 storage pair index
        const int s  = cp << 1;            // even storage col
        const int kc = s >> 5, rr = s & 31, gg = rr >> 3, jj = rr & 7;
        const int cA = kc * 32 + gg * 4 + (jj & 3) + 16 * (jj >> 2);  // actual ch (pair cA,cA+1)

        const int gw = w0 + wq * 4;
        const bool l_edge = (gw == 0);
        const bool r_edge = (gw + 4 >= WW);

        const float* planeA = x + (size_t)(bb * CC + cA) * (HH * WW);
        const float* planeB = planeA + HH * WW;

        // 18 contiguous weight floats (rows cA, cA+1 of kk)
        float kwA[9], kwB[9];
        {
            const float* kp = kk + (size_t)(bb * CC + cA) * 9;
            f32x4u_t q0 = *(const f32x4u_t*)(kp + 0);
            f32x4u_t q1 = *(const f32x4u_t*)(kp + 4);
            f32x4u_t q2 = *(const f32x4u_t*)(kp + 8);
            f32x4u_t q3 = *(const f32x4u_t*)(kp + 12);
            float     e16 = kp[16], e17 = kp[17];
            kwA[0]=q0.x; kwA[1]=q0.y; kwA[2]=q0.z; kwA[3]=q0.w;
            kwA[4]=q1.x; kwA[5]=q1.y; kwA[6]=q1.z; kwA[7]=q1.w;
            kwA[8]=q2.x;
            kwB[0]=q2.y; kwB[1]=q2.z; kwB[2]=q2.w;
            kwB[3]=q3.x; kwB[4]=q3.y; kwB[5]=q3.z; kwB[6]=q3.w;
            kwB[7]=e16;  kwB[8]=e17;
        }

        float rT[2][6], rM[2][6];   // top/mid rows of 6-wide window, 2 channels

        auto load6 = [&](const float* plane, int row, float* o) {
            if (row < 0 || row >= HH) {
                #pragma unroll
                for (int t = 0; t < 6; ++t) o[t] = 0.f;
                return;
            }
            const float* rp = plane + row * WW + gw;   // 16B aligned
            f32x4_t M = *(const f32x4_t*)rp;
            float vl = rp[l_edge ? 0 : -1];            // clamped addr, value masked
            float vr = rp[r_edge ? 3 : 4];
            o[0] = l_edge ? 0.f : vl;
            o[1] = M.x; o[2] = M.y; o[3] = M.z; o[4] = M.w;
            o[5] = r_edge ? 0.f : vr;
        };

        load6(planeA, h0 - 1, rT[0]); load6(planeB, h0 - 1, rT[1]);
        load6(planeA, h0,     rM[0]); load6(planeB, h0,     rM[1]);

        #pragma unroll
        for (int py = 0; py < 8; ++py) {
            float rBt[2][6];
            load6(planeA, h0 + py + 1, rBt[0]);
            load6(planeB, h0 + py + 1, rBt[1]);

            unsigned pk[4];
            #pragma unroll
            for (int i = 0; i < 4; ++i) {
                float sA = 0.f, sB = 0.f;
                #pragma unroll
                for (int t = 0; t < 3; ++t) {
                    sA = fmaf(rT[0][i + t],  kwA[t],     sA);
                    sA = fmaf(rM[0][i + t],  kwA[3 + t], sA);
                    sA = fmaf(rBt[0][i + t], kwA[6 + t], sA);
                    sB = fmaf(rT[1][i + t],  kwB[t],     sB);
                    sB = fmaf(rM[1][i + t],  kwB[3 + t], sB);
                    sB = fmaf(rBt[1][i + t], kwB[6 + t], sB);
                }
                __hip_bfloat16 hA = __float2bfloat16(sA);
                __hip_bfloat16 hB = __float2bfloat16(sB);
                unsigned lo16 = *reinterpret_cast<unsigned short*>(&hA);
                unsigned hi16 = *reinterpret_cast<unsigned short*>(&hB);
                pk[i] = lo16 | (hi16 << 16);
            }
            #pragma unroll
            for (int i = 0; i < 4; ++i) {
                const int p = py * 16 + wq * 4 + i;
                const unsigned boff = ((unsigned)(cp << 2)) ^ (((unsigned)p & 7u) << 4);
                *reinterpret_cast<unsigned*>(&xnb[(unsigned)p * 256 + boff]) = pk[i];
            }
            #pragma unroll
            for (int q = 0; q < 2; ++q)
                #pragma unroll
                for (int t = 0; t < 6; ++t) { rT[q][t] = rM[q][t]; rM[q][t] = rBt[q][t]; }
        }
    }

    __syncthreads();

    // ---------------- stage 2: MFMA pointwise + BN + ReLU (verified in R3) ----------------
    {
        const int lane   = tid & 63;
        const int wv     = tid >> 6;       // 0..3
        const int lo     = lane & 15;
        const int hi     = lane >> 4;
        const int o_base = wv * 32;

        // A fragments (W): 2 o-tiles x 4 k-chunks, one 16B load each
        bf16x8_t afrag[2][4];
        #pragma unroll
        for (int t2 = 0; t2 < 2; ++t2)
            #pragma unroll
            for (int kc = 0; kc < 4; ++kc)
                afrag[t2][kc] = *reinterpret_cast<const bf16x8_t*>(
                    wper + (size_t)(o_base + t2 * 16 + lo) * CC + kc * 32 + hi * 8);

        f32x4_t acc[8][2];
        #pragma unroll
        for (int pt = 0; pt < 8; ++pt) {
            acc[pt][0] = (f32x4_t){0.f, 0.f, 0.f, 0.f};
            acc[pt][1] = (f32x4_t){0.f, 0.f, 0.f, 0.f};
        }

        #pragma unroll
        for (int pt = 0; pt < 8; ++pt) {
            const unsigned rowbase = (unsigned)(pt * 16 + lo) * 256;
            const unsigned sw = (unsigned)((lo & 7) << 4);
            #pragma unroll
            for (int kc = 0; kc < 4; ++kc) {
                bf16x8_t bfrag = *reinterpret_cast<const bf16x8_t*>(
                    &xnb[rowbase + (((unsigned)(kc * 64 + hi * 16)) ^ sw)]);
                acc[pt][0] = __builtin_amdgcn_mfma_f32_16x16x32_bf16(
                    afrag[0][kc], bfrag, acc[pt][0], 0, 0, 0);
                acc[pt][1] = __builtin_amdgcn_mfma_f32_16x16x32_bf16(
                    afrag[1][kc], bfrag, acc[pt][1], 0, 0, 0);
            }
        }

        float iv[2][4], bs[2][4];
        #pragma unroll
        for (int t2 = 0; t2 < 2; ++t2)
            #pragma unroll
            for (int r = 0; r < 4; ++r) {
                const int o = o_base + t2 * 16 + hi * 4 + r;
                iv[t2][r] = invp[o];
                bs[t2][r] = biasp[o];
            }

        #pragma unroll
        for (int pt = 0; pt < 8; ++pt) {
            const int hrow = h0 + pt;
            #pragma unroll
            for (int t2 = 0; t2 < 2; ++t2) {
                #pragma unroll
                for (int r = 0; r < 4; ++r) {
                    const int o = o_base + t2 * 16 + hi * 4 + r;
                    float val = fmaf(acc[pt][t2][r], iv[t2][r], bs[t2][r]);
                    val = fmaxf(val, 0.f);
                    out[((size_t)(bb * CC + o) * HH + hrow) * WW + w0 + lo] = val;
                }
            }
        }
    }
}

extern "C" void kernel_launch(void* const* d_in, const int* in_sizes, int n_in,
                              void* d_out, int out_size, void* d_ws, size_t ws_size,
                              hipStream_t stream) {
    const float* x   = (const float*)d_in[0];
    const float* kk  = (const float*)d_in[1];
    const float* pwt = (const float*)d_in[2];
    const float* g   = (const float*)d_in[3];
    const float* b   = (const float*)d_in[4];
    const float* m   = (const float*)d_in[5];
    const float* v   = (const float*)d_in[6];
    float* out = (float*)d_out;

    unsigned short* wper = (unsigned short*)d_ws;                 // 32 KB
    float* inv  = (float*)((char*)d_ws + 32768);                  // 512 B
    float* bias = (float*)((char*)d_ws + 32768 + 512);            // 512 B

    prep_kernel<<<64, 256, 0, stream>>>(pwt, g, b, m, v, wper, inv, bias);
    fused_main<<<dim3(WW / 16, HH / 8, BB), 256, 0, stream>>>(
        x, kk, wper, inv, bias, out);
}

// Round 5
// 126.583 us; speedup vs baseline: 5.5626x; 1.0480x over previous
//
#include <hip/hip_runtime.h>
#include <hip/hip_bf16.h>

#define BB 32
#define CC 128
#define HH 96
#define WW 96
#define BN_EPS 1e-5f

typedef __attribute__((ext_vector_type(8))) short bf16x8_t;
typedef __attribute__((ext_vector_type(4))) float f32x4_t;
typedef __attribute__((ext_vector_type(4), aligned(4))) float f32x4u_t;

// ---------------------------------------------------------------------------
// Prep: W fp32 -> bf16, k-permuted for mfma_f32_16x16x32_bf16 split-k frags
//   storage cidx = kc*32 + g*8 + j  <->  actual c = kc*32 + g*4 + (j&3) + 16*(j>>2)
// Also folds BN to inv/bias.   (unchanged — verified)
// ---------------------------------------------------------------------------
__global__ __launch_bounds__(256)
void prep_kernel(const float* __restrict__ pw,
                 const float* __restrict__ g, const float* __restrict__ b,
                 const float* __restrict__ m, const float* __restrict__ v,
                 unsigned short* __restrict__ wper,
                 float* __restrict__ inv, float* __restrict__ bias)
{
    int t = blockIdx.x * 256 + threadIdx.x;
    if (t < CC * CC) {
        int o = t >> 7, cidx = t & 127;
        int kc = cidx >> 5, r = cidx & 31, gg = r >> 3, j = r & 7;
        int c = kc * 32 + gg * 4 + (j & 3) + 16 * (j >> 2);
        __hip_bfloat16 h = __float2bfloat16(pw[o * CC + c]);
        wper[o * CC + cidx] = *reinterpret_cast<unsigned short*>(&h);
    }
    if (t < CC) {
        float iv = g[t] * rsqrtf(v[t] + BN_EPS);
        inv[t] = iv;
        bias[t] = b[t] - m[t] * iv;
    }
}

// ---------------------------------------------------------------------------
// Main: one block = batch bb x (16w x 8h) tile, all 128 channels.
// R5: (1) stage-1 loads ALL 10 rows x 2 channels upfront (static xd[2][10][6],
//     ~120 VGPR) so all 65 VMEM issue as one independent burst (R4's 60-VGPR
//     sliding window serialized them); launch_bounds(256,3).
//     (2) flat grid + chunked XCD swizzle (T1): 2304 blocks = 8 x 288, each
//     XCD gets a contiguous bx-fastest chunk -> halo cache lines reused in
//     one XCD's L2 (R4 fetch was 2.0x input from cross-XCD round-robin).
// Stage 2: bf16 MFMA 128x128x128 + BN + ReLU (unchanged — verified).
// LDS xn[p][c_storage] bf16, byte-swizzle boff ^= (p&7)<<4 on both sides.
// ---------------------------------------------------------------------------
__global__ __launch_bounds__(256, 3)
void fused_main(const float* __restrict__ x, const float* __restrict__ kk,
                const unsigned short* __restrict__ wper,
                const float* __restrict__ invp, const float* __restrict__ biasp,
                float* __restrict__ out)
{
    __shared__ __align__(16) unsigned char xnb[128 * 256];

    const int tid = threadIdx.x;

    // chunked XCD swizzle (bijective: 2304 % 8 == 0)
    const unsigned wg  = blockIdx.x;
    const unsigned nid = (wg & 7u) * 288u + (wg >> 3);
    const int bx = nid % 6u;
    const int by = (nid / 6u) % 12u;
    const int bb = nid / 72u;
    const int w0 = bx * 16;
    const int h0 = by * 8;

    // ---------------- stage 1: depthwise ----------------
    {
        const int wq = tid & 3;            // 4-wide w quad
        const int cp = tid >> 2;           // 0..63 storage pair index
        const int s  = cp << 1;            // even storage col
        const int kc = s >> 5, rr = s & 31, gg = rr >> 3, jj = rr & 7;
        const int cA = kc * 32 + gg * 4 + (jj & 3) + 16 * (jj >> 2);  // pair cA, cA+1

        const int gw = w0 + wq * 4;
        const bool l_edge = (gw == 0);
        const bool r_edge = (gw + 4 >= WW);

        const float* planeA = x + (size_t)(bb * CC + cA) * (HH * WW);

        // 18 contiguous weight floats (rows cA, cA+1 of kk)
        float kwA[9], kwB[9];
        {
            const float* kp = kk + (size_t)(bb * CC + cA) * 9;
            f32x4u_t q0 = *(const f32x4u_t*)(kp + 0);
            f32x4u_t q1 = *(const f32x4u_t*)(kp + 4);
            f32x4u_t q2 = *(const f32x4u_t*)(kp + 8);
            f32x4u_t q3 = *(const f32x4u_t*)(kp + 12);
            float     e16 = kp[16], e17 = kp[17];
            kwA[0]=q0.x; kwA[1]=q0.y; kwA[2]=q0.z; kwA[3]=q0.w;
            kwA[4]=q1.x; kwA[5]=q1.y; kwA[6]=q1.z; kwA[7]=q1.w;
            kwA[8]=q2.x;
            kwB[0]=q2.y; kwB[1]=q2.z; kwB[2]=q2.w;
            kwB[3]=q3.x; kwB[4]=q3.y; kwB[5]=q3.z; kwB[6]=q3.w;
            kwB[7]=e16;  kwB[8]=e17;
        }

        // upfront load: all 10 rows x 2 channels, fully static -> registers
        float xd[2][10][6];
        #pragma unroll
        for (int q = 0; q < 2; ++q) {
            const float* plane = planeA + q * (HH * WW);
            #pragma unroll
            for (int r = 0; r < 10; ++r) {
                const int row = h0 - 1 + r;
                const bool valid = (row >= 0) && (row < HH);     // block-uniform
                const int rrow = row < 0 ? 0 : (row >= HH ? HH - 1 : row);
                const float* rp = plane + rrow * WW + gw;        // 16B aligned
                f32x4_t M = *(const f32x4_t*)rp;
                float vl = rp[l_edge ? 0 : -1];
                float vr = rp[r_edge ? 3 : 4];
                xd[q][r][0] = (valid && !l_edge) ? vl : 0.f;
                xd[q][r][1] = valid ? M.x : 0.f;
                xd[q][r][2] = valid ? M.y : 0.f;
                xd[q][r][3] = valid ? M.z : 0.f;
                xd[q][r][4] = valid ? M.w : 0.f;
                xd[q][r][5] = (valid && !r_edge) ? vr : 0.f;
            }
        }

        #pragma unroll
        for (int py = 0; py < 8; ++py) {
            #pragma unroll
            for (int i = 0; i < 4; ++i) {
                float sA = 0.f, sB = 0.f;
                #pragma unroll
                for (int t = 0; t < 3; ++t) {
                    sA = fmaf(xd[0][py + 0][i + t], kwA[t],     sA);
                    sA = fmaf(xd[0][py + 1][i + t], kwA[3 + t], sA);
                    sA = fmaf(xd[0][py + 2][i + t], kwA[6 + t], sA);
                    sB = fmaf(xd[1][py + 0][i + t], kwB[t],     sB);
                    sB = fmaf(xd[1][py + 1][i + t], kwB[3 + t], sB);
                    sB = fmaf(xd[1][py + 2][i + t], kwB[6 + t], sB);
                }
                __hip_bfloat16 hA = __float2bfloat16(sA);
                __hip_bfloat16 hB = __float2bfloat16(sB);
                unsigned pk = (unsigned)*reinterpret_cast<unsigned short*>(&hA)
                            | ((unsigned)*reinterpret_cast<unsigned short*>(&hB) << 16);
                const int p = py * 16 + wq * 4 + i;
                const unsigned boff = ((unsigned)(cp << 2)) ^ (((unsigned)p & 7u) << 4);
                *reinterpret_cast<unsigned*>(&xnb[(unsigned)p * 256 + boff]) = pk;
            }
        }
    }

    __syncthreads();

    // ---------------- stage 2: MFMA pointwise + BN + ReLU (verified) ----------------
    {
        const int lane   = tid & 63;
        const int wv     = tid >> 6;       // 0..3
        const int lo     = lane & 15;
        const int hi     = lane >> 4;
        const int o_base = wv * 32;

        bf16x8_t afrag[2][4];
        #pragma unroll
        for (int t2 = 0; t2 < 2; ++t2)
            #pragma unroll
            for (int kc = 0; kc < 4; ++kc)
                afrag[t2][kc] = *reinterpret_cast<const bf16x8_t*>(
                    wper + (size_t)(o_base + t2 * 16 + lo) * CC + kc * 32 + hi * 8);

        f32x4_t acc[8][2];
        #pragma unroll
        for (int pt = 0; pt < 8; ++pt) {
            acc[pt][0] = (f32x4_t){0.f, 0.f, 0.f, 0.f};
            acc[pt][1] = (f32x4_t){0.f, 0.f, 0.f, 0.f};
        }

        #pragma unroll
        for (int pt = 0; pt < 8; ++pt) {
            const unsigned rowbase = (unsigned)(pt * 16 + lo) * 256;
            const unsigned sw = (unsigned)((lo & 7) << 4);
            #pragma unroll
            for (int kc = 0; kc < 4; ++kc) {
                bf16x8_t bfrag = *reinterpret_cast<const bf16x8_t*>(
                    &xnb[rowbase + (((unsigned)(kc * 64 + hi * 16)) ^ sw)]);
                acc[pt][0] = __builtin_amdgcn_mfma_f32_16x16x32_bf16(
                    afrag[0][kc], bfrag, acc[pt][0], 0, 0, 0);
                acc[pt][1] = __builtin_amdgcn_mfma_f32_16x16x32_bf16(
                    afrag[1][kc], bfrag, acc[pt][1], 0, 0, 0);
            }
        }

        float iv[2][4], bs[2][4];
        #pragma unroll
        for (int t2 = 0; t2 < 2; ++t2)
            #pragma unroll
            for (int r = 0; r < 4; ++r) {
                const int o = o_base + t2 * 16 + hi * 4 + r;
                iv[t2][r] = invp[o];
                bs[t2][r] = biasp[o];
            }

        #pragma unroll
        for (int pt = 0; pt < 8; ++pt) {
            const int hrow = h0 + pt;
            #pragma unroll
            for (int t2 = 0; t2 < 2; ++t2) {
                #pragma unroll
                for (int r = 0; r < 4; ++r) {
                    const int o = o_base + t2 * 16 + hi * 4 + r;
                    float val = fmaf(acc[pt][t2][r], iv[t2][r], bs[t2][r]);
                    val = fmaxf(val, 0.f);
                    out[((size_t)(bb * CC + o) * HH + hrow) * WW + w0 + lo] = val;
                }
            }
        }
    }
}

extern "C" void kernel_launch(void* const* d_in, const int* in_sizes, int n_in,
                              void* d_out, int out_size, void* d_ws, size_t ws_size,
                              hipStream_t stream) {
    const float* x   = (const float*)d_in[0];
    const float* kk  = (const float*)d_in[1];
    const float* pwt = (const float*)d_in[2];
    const float* g   = (const float*)d_in[3];
    const float* b   = (const float*)d_in[4];
    const float* m   = (const float*)d_in[5];
    const float* v   = (const float*)d_in[6];
    float* out = (float*)d_out;

    unsigned short* wper = (unsigned short*)d_ws;                 // 32 KB
    float* inv  = (float*)((char*)d_ws + 32768);                  // 512 B
    float* bias = (float*)((char*)d_ws + 32768 + 512);            // 512 B

    prep_kernel<<<64, 256, 0, stream>>>(pwt, g, b, m, v, wper, inv, bias);
    fused_main<<<dim3(6 * 12 * BB), 256, 0, stream>>>(x, kk, wper, inv, bias, out);
}